// Round 3
// baseline (151.607 us; speedup 1.0000x reference)
//
#include <hip/hip_runtime.h>
#include <hip/hip_bf16.h>
#include <stdint.h>

#define SQ_  4096
#define SK_  4096
#define D_   1024
#define DV_  1024

typedef __attribute__((ext_vector_type(4))) float  f32x4;
typedef __attribute__((ext_vector_type(4))) int    i32x4;
typedef __attribute__((ext_vector_type(8))) int    i32x8;

__device__ __forceinline__ unsigned char f2fp8(float v) {
  int d = __builtin_amdgcn_cvt_pk_fp8_f32(v, v, 0, false);
  return (unsigned char)(d & 0xff);
}

__device__ __forceinline__ void gload_lds16(const void* gp, void* lp) {
  auto g1 = reinterpret_cast<__attribute__((address_space(1))) uint32_t*>(
      reinterpret_cast<uintptr_t>(gp));
  auto l3 = reinterpret_cast<__attribute__((address_space(3))) uint32_t*>(
      reinterpret_cast<uintptr_t>(lp));
  __builtin_amdgcn_global_load_lds(g1, l3, 16, 0, 0);
}

// ---------------- fp32 -> fp8 e4m3 (OCP) conversion, 8/thread ---------------
__global__ void conv8_kernel(const float* __restrict__ in,
                             unsigned int* __restrict__ out, int n8) {
  int i = blockIdx.x * blockDim.x + threadIdx.x;
  if (i >= n8) return;
  const float4* p = reinterpret_cast<const float4*>(in) + (size_t)i * 2;
  float4 v0 = p[0], v1 = p[1];
  int d0 = __builtin_amdgcn_cvt_pk_fp8_f32(v0.x, v0.y, 0, false);
  d0     = __builtin_amdgcn_cvt_pk_fp8_f32(v0.z, v0.w, d0, true);
  int d1 = __builtin_amdgcn_cvt_pk_fp8_f32(v1.x, v1.y, 0, false);
  d1     = __builtin_amdgcn_cvt_pk_fp8_f32(v1.z, v1.w, d1, true);
  uint2 o; o.x = (unsigned)d0; o.y = (unsigned)d1;
  reinterpret_cast<uint2*>(out)[i] = o;
}

// ------- column partial sums of e8 (fp8, deterministic) ----------------------
// thread handles 4 consecutive cols (one uint) x 128 rows.
__global__ void colsum8_part_kernel(const unsigned char* __restrict__ e8,
                                    float* __restrict__ part) {
  int j4 = blockIdx.x * 256 + threadIdx.x;     // uint index, SK_/4 per row
  int i0 = blockIdx.y * 128;
  const unsigned int* p =
      reinterpret_cast<const unsigned int*>(e8) + (size_t)i0 * (SK_ / 4) + j4;
  float s0 = 0.f, s1 = 0.f, s2 = 0.f, s3 = 0.f;
  #pragma unroll 8
  for (int i = 0; i < 128; ++i) {
    unsigned int w = *p;
    s0 += __builtin_amdgcn_cvt_f32_fp8(w, 0);
    s1 += __builtin_amdgcn_cvt_f32_fp8(w, 1);
    s2 += __builtin_amdgcn_cvt_f32_fp8(w, 2);
    s3 += __builtin_amdgcn_cvt_f32_fp8(w, 3);
    p += SK_ / 4;
  }
  float4 o; o.x = s0; o.y = s1; o.z = s2; o.w = s3;
  reinterpret_cast<float4*>(part + (size_t)blockIdx.y * SK_ + j4 * 4)[0] = o;
}

// l_j = 4096 + (sum_i e8[i][j]) / 16   (e8 stores 16*expm1(s))
__global__ void colsum8_fin_kernel(const float* __restrict__ part,
                                   float* __restrict__ l) {
  int j = blockIdx.x * 256 + threadIdx.x;
  float s = 0.f;
  #pragma unroll
  for (int y = 0; y < 32; ++y) s += part[(size_t)y * SK_ + j];
  l[j] = 4096.0f + s * (1.0f / 16.0f);
}

// ------- V''t[d][j] = fp8(V[j][d]*4096/l[j])  +  CS partials ----------------
// CS[d] = sum_j V[j][d]/l[j]; block covers 64 j x 64 d.
__global__ void transv_cs_kernel(const float* __restrict__ V,
                                 const float* __restrict__ l,
                                 unsigned char* __restrict__ V8t,
                                 float* __restrict__ cs_part) {
  __shared__ float tile[64][65];
  __shared__ float linv[64];
  int j0 = blockIdx.x * 64;           // SK dim
  int d0 = blockIdx.y * 64;           // DV dim
  int t  = threadIdx.x;
  int tr = t >> 6;                    // 0..3
  int tc = t & 63;                    // 0..63
  if (t < 64) linv[t] = 1.0f / l[j0 + t];
  #pragma unroll
  for (int rr = 0; rr < 16; ++rr) {
    int j = rr * 4 + tr;
    tile[j][tc] = V[(size_t)(j0 + j) * DV_ + d0 + tc];
  }
  __syncthreads();
  // V''t write: thread (tr,tc) -> j = tc, d = rr*4+tr
  float sc = 4096.0f * linv[tc];
  #pragma unroll
  for (int rr = 0; rr < 16; ++rr) {
    int d = rr * 4 + tr;
    V8t[(size_t)(d0 + d) * SK_ + j0 + tc] = f2fp8(tile[tc][d] * sc);
  }
  // CS partial: thread (tr,tc) -> d = tc, j in [tr*16, tr*16+16)
  float s = 0.f;
  #pragma unroll
  for (int jj = 0; jj < 16; ++jj) {
    int j = tr * 16 + jj;
    s += tile[j][tc] * linv[j];
  }
  cs_part[(size_t)(blockIdx.x * 4 + tr) * DV_ + d0 + tc] = s;
}

__global__ void cs_fin_kernel(const float* __restrict__ cs_part,
                              float* __restrict__ CS) {
  int d = blockIdx.x * 256 + threadIdx.x;
  float s = 0.f;
  #pragma unroll
  for (int p = 0; p < 256; ++p) s += cs_part[(size_t)p * DV_ + d];
  CS[d] = s;
}

// ============ fp8 MX GEMM: acc = A*B^T (A [M][K], B [N][K], K contig) ========
// MODE 0: store fp8(16*expm1(acc*scale))          (GEMM1: E-residual)
// MODE 1: store fp32 CS[col] + acc/65536          (GEMM2: output)
// LDS rows 128B = 8 x 16B slots, XOR-swizzled; gload_lds src pre-swizzled.
template <int FM, int FN, int MODE>
__global__ __launch_bounds__(256, 2)
void gemm8_kernel(const unsigned char* __restrict__ A,
                  const unsigned char* __restrict__ B,
                  void* __restrict__ Cout,
                  const float* __restrict__ CS,
                  int N, int K, float scale) {
  constexpr int BM = FM * 32;
  constexpr int BN = FN * 32;
  __shared__ __align__(16) unsigned char As[BM * 128];
  __shared__ __align__(16) unsigned char Bs[BN * 128];

  const int t    = threadIdx.x;
  const int lane = t & 63;
  const int wave = t >> 6;
  const int wr   = wave >> 1, wc = wave & 1;
  const int lr   = lane & 15;         // row(A frag) / col(B frag) / D col
  const int lk   = lane >> 4;         // k-block 0..3 (32 bytes each)

  const int m0 = blockIdx.y * BM;
  const int n0 = blockIdx.x * BN;

  f32x4 acc[FM][FN] = {};

  for (int k0 = 0; k0 < K; k0 += 128) {
    #pragma unroll
    for (int it = 0; it < FM; ++it) {
      int s = it * 256 + t;
      int row = s >> 3, p = s & 7;
      int k16 = p ^ (row & 7);
      gload_lds16(A + (size_t)(m0 + row) * K + k0 + k16 * 16, As + s * 16);
    }
    #pragma unroll
    for (int it = 0; it < FN; ++it) {
      int s = it * 256 + t;
      int row = s >> 3, p = s & 7;
      int k16 = p ^ (row & 7);
      gload_lds16(B + (size_t)(n0 + row) * K + k0 + k16 * 16, Bs + s * 16);
    }
    __syncthreads();

    i32x8 af[FM], bfr[FN];
    #pragma unroll
    for (int m = 0; m < FM; ++m) {
      int r = wr * (FM * 16) + m * 16 + lr;
      int s0 = (2 * lk) ^ (r & 7), s1 = (2 * lk + 1) ^ (r & 7);
      i32x4 lo = *reinterpret_cast<const i32x4*>(As + r * 128 + s0 * 16);
      i32x4 hi = *reinterpret_cast<const i32x4*>(As + r * 128 + s1 * 16);
      af[m][0] = lo[0]; af[m][1] = lo[1]; af[m][2] = lo[2]; af[m][3] = lo[3];
      af[m][4] = hi[0]; af[m][5] = hi[1]; af[m][6] = hi[2]; af[m][7] = hi[3];
    }
    #pragma unroll
    for (int n = 0; n < FN; ++n) {
      int r = wc * (FN * 16) + n * 16 + lr;
      int s0 = (2 * lk) ^ (r & 7), s1 = (2 * lk + 1) ^ (r & 7);
      i32x4 lo = *reinterpret_cast<const i32x4*>(Bs + r * 128 + s0 * 16);
      i32x4 hi = *reinterpret_cast<const i32x4*>(Bs + r * 128 + s1 * 16);
      bfr[n][0] = lo[0]; bfr[n][1] = lo[1]; bfr[n][2] = lo[2]; bfr[n][3] = lo[3];
      bfr[n][4] = hi[0]; bfr[n][5] = hi[1]; bfr[n][6] = hi[2]; bfr[n][7] = hi[3];
    }
    #pragma unroll
    for (int m = 0; m < FM; ++m)
      #pragma unroll
      for (int n = 0; n < FN; ++n)
        acc[m][n] = __builtin_amdgcn_mfma_scale_f32_16x16x128_f8f6f4(
            af[m], bfr[n], acc[m][n], 0, 0, 0, 127, 0, 127);
    __syncthreads();
  }

  const int orow0 = m0 + wr * (FM * 16) + lk * 4;
  const int ocol0 = n0 + wc * (FN * 16) + lr;
  if constexpr (MODE == 0) {
    unsigned char* E8 = (unsigned char*)Cout;
    #pragma unroll
    for (int m = 0; m < FM; ++m)
      #pragma unroll
      for (int n = 0; n < FN; ++n)
        #pragma unroll
        for (int r = 0; r < 4; ++r) {
          float s = acc[m][n][r] * scale;
          float e = s + 0.5f * s * s + (1.0f / 6.0f) * s * s * s;  // expm1
          E8[(size_t)(orow0 + m * 16 + r) * N + (ocol0 + n * 16)] =
              f2fp8(e * 16.0f);
        }
  } else {
    float* O = (float*)Cout;
    #pragma unroll
    for (int m = 0; m < FM; ++m)
      #pragma unroll
      for (int n = 0; n < FN; ++n) {
        float cs = CS[ocol0 + n * 16];
        #pragma unroll
        for (int r = 0; r < 4; ++r)
          O[(size_t)(orow0 + m * 16 + r) * N + (ocol0 + n * 16)] =
              cs + acc[m][n][r] * (1.0f / 65536.0f);
      }
  }
}

extern "C" void kernel_launch(void* const* d_in, const int* in_sizes, int n_in,
                              void* d_out, int out_size, void* d_ws,
                              size_t ws_size, hipStream_t stream) {
  const float* Q = (const float*)d_in[0];
  const float* K = (const float*)d_in[1];
  const float* V = (const float*)d_in[2];

  char* ws = (char*)d_ws;
  unsigned char* Q8    = (unsigned char*)(ws);                         // 4 MB
  unsigned char* K8    = (unsigned char*)(ws + ((size_t)4 << 20));     // 4 MB
  unsigned char* e8    = (unsigned char*)(ws + ((size_t)8 << 20));     // 16 MB
  unsigned char* V8t   = (unsigned char*)(ws + ((size_t)24 << 20));    // 4 MB
  float*         l     = (float*)(ws + ((size_t)28 << 20));            // 16 KB
  float*         part  = (float*)(ws + ((size_t)28 << 20) + (64 << 10));   // 512 KB
  float*         csp   = (float*)(ws + ((size_t)29 << 20));            // 1 MB
  float*         CS    = (float*)(ws + ((size_t)30 << 20));            // 4 KB

  conv8_kernel<<<SQ_ * D_ / 8 / 256, 256, 0, stream>>>(Q, (unsigned*)Q8,
                                                       SQ_ * D_ / 8);
  conv8_kernel<<<SK_ * D_ / 8 / 256, 256, 0, stream>>>(K, (unsigned*)K8,
                                                       SK_ * D_ / 8);

  // e8 = fp8(16*expm1(Q K^T / SK))
  gemm8_kernel<4, 4, 0><<<dim3(SK_ / 128, SQ_ / 128), 256, 0, stream>>>(
      Q8, K8, (void*)e8, nullptr, SK_, D_, 1.0f / (float)SK_);

  // l_j = 4096 + sum_i e8[i][j]/16
  colsum8_part_kernel<<<dim3(SK_ / 1024, SQ_ / 128), 256, 0, stream>>>(e8, part);
  colsum8_fin_kernel<<<SK_ / 256, 256, 0, stream>>>(part, l);

  // V''t[d][j] = fp8(V[j][d]*4096/l[j]); CS[d] = sum_j V[j][d]/l[j]
  transv_cs_kernel<<<dim3(SK_ / 64, DV_ / 64), 256, 0, stream>>>(V, l, V8t, csp);
  cs_fin_kernel<<<DV_ / 256, 256, 0, stream>>>(csp, CS);

  // O[i][d] = CS[d] + (e8 @ V''t^T)/65536
  gemm8_kernel<2, 4, 1><<<dim3(DV_ / 128, SQ_ / 64), 256, 0, stream>>>(
      e8, V8t, d_out, CS, DV_, SK_, 1.0f);

  (void)in_sizes; (void)n_in; (void)out_size; (void)ws_size;
}

// Round 4
// 88.699 us; speedup vs baseline: 1.7092x; 1.7092x over previous
//
#include <hip/hip_runtime.h>
#include <hip/hip_bf16.h>
#include <stdint.h>

#define SQ_  4096
#define SK_  4096
#define D_   1024
#define DV_  1024

typedef __attribute__((ext_vector_type(4))) float  f32x4;
typedef __attribute__((ext_vector_type(4))) int    i32x4;
typedef __attribute__((ext_vector_type(8))) int    i32x8;

__device__ __forceinline__ unsigned char f2fp8(float v) {
  int d = __builtin_amdgcn_cvt_pk_fp8_f32(v, v, 0, false);
  return (unsigned char)(d & 0xff);
}

__device__ __forceinline__ void gload_lds16(const void* gp, void* lp) {
  auto g1 = reinterpret_cast<__attribute__((address_space(1))) uint32_t*>(
      reinterpret_cast<uintptr_t>(gp));
  auto l3 = reinterpret_cast<__attribute__((address_space(3))) uint32_t*>(
      reinterpret_cast<uintptr_t>(lp));
  __builtin_amdgcn_global_load_lds(g1, l3, 16, 0, 0);
}

// ---------------- fp32 -> fp8 e4m3 (OCP) conversion, 8/thread ---------------
__global__ void conv8_kernel(const float* __restrict__ in,
                             unsigned int* __restrict__ out, int n8) {
  int i = blockIdx.x * blockDim.x + threadIdx.x;
  if (i >= n8) return;
  const float4* p = reinterpret_cast<const float4*>(in) + (size_t)i * 2;
  float4 v0 = p[0], v1 = p[1];
  int d0 = __builtin_amdgcn_cvt_pk_fp8_f32(v0.x, v0.y, 0, false);
  d0     = __builtin_amdgcn_cvt_pk_fp8_f32(v0.z, v0.w, d0, true);
  int d1 = __builtin_amdgcn_cvt_pk_fp8_f32(v1.x, v1.y, 0, false);
  d1     = __builtin_amdgcn_cvt_pk_fp8_f32(v1.z, v1.w, d1, true);
  uint2 o; o.x = (unsigned)d0; o.y = (unsigned)d1;
  reinterpret_cast<uint2*>(out)[i] = o;
}

// ------- column partial sums of e8 (fp8, deterministic) ----------------------
// grid (SK_/1024, SQ_/64): thread handles 4 consecutive cols x 64 rows.
__global__ void colsum8_part_kernel(const unsigned char* __restrict__ e8,
                                    float* __restrict__ part) {
  int j4 = blockIdx.x * 256 + threadIdx.x;     // uint index, SK_/4 per row
  int i0 = blockIdx.y * 64;
  const unsigned int* p =
      reinterpret_cast<const unsigned int*>(e8) + (size_t)i0 * (SK_ / 4) + j4;
  float s0 = 0.f, s1 = 0.f, s2 = 0.f, s3 = 0.f;
  #pragma unroll 8
  for (int i = 0; i < 64; ++i) {
    unsigned int w = *p;
    s0 += __builtin_amdgcn_cvt_f32_fp8(w, 0);
    s1 += __builtin_amdgcn_cvt_f32_fp8(w, 1);
    s2 += __builtin_amdgcn_cvt_f32_fp8(w, 2);
    s3 += __builtin_amdgcn_cvt_f32_fp8(w, 3);
    p += SK_ / 4;
  }
  float4 o; o.x = s0; o.y = s1; o.z = s2; o.w = s3;
  reinterpret_cast<float4*>(part + (size_t)blockIdx.y * SK_ + j4 * 4)[0] = o;
}

// l_j = 4096 + (sum of 64 partials)/16.  grid SK_/64, 2-D parallel reduce.
__global__ void colsum8_fin_kernel(const float* __restrict__ part,
                                   float* __restrict__ l) {
  __shared__ float red[4][64];
  int j0 = blockIdx.x * 64;
  int t  = threadIdx.x;
  int jj = t & 63, pg = t >> 6;               // 4 partial-groups x 64 cols
  float s = 0.f;
  #pragma unroll
  for (int k = 0; k < 16; ++k)
    s += part[(size_t)(pg * 16 + k) * SK_ + j0 + jj];
  red[pg][jj] = s;
  __syncthreads();
  if (pg == 0) {
    float tot = red[0][jj] + red[1][jj] + red[2][jj] + red[3][jj];
    l[j0 + jj] = 4096.0f + tot * (1.0f / 16.0f);
  }
}

// ------- V''t[d][j] = fp8(V[j][d]*4096/l[j])  +  CS partials ----------------
// CS[d] = sum_j V[j][d]/l[j]; block covers 64 j x 64 d; writes ONE partial
// per (j-block, d) -> cs_part layout [SK_/64][DV].
__global__ void transv_cs_kernel(const float* __restrict__ V,
                                 const float* __restrict__ l,
                                 unsigned char* __restrict__ V8t,
                                 float* __restrict__ cs_part) {
  __shared__ float tile[64][65];
  __shared__ float linv[64];
  __shared__ float csred[4][64];
  int j0 = blockIdx.x * 64;           // SK dim
  int d0 = blockIdx.y * 64;           // DV dim
  int t  = threadIdx.x;
  int tr = t >> 6;                    // 0..3
  int tc = t & 63;                    // 0..63
  if (t < 64) linv[t] = 1.0f / l[j0 + t];
  #pragma unroll
  for (int rr = 0; rr < 16; ++rr) {
    int j = rr * 4 + tr;
    tile[j][tc] = V[(size_t)(j0 + j) * DV_ + d0 + tc];
  }
  __syncthreads();
  // V''t write: thread (tr,tc) -> j = tc, d = rr*4+tr
  float sc = 4096.0f * linv[tc];
  #pragma unroll
  for (int rr = 0; rr < 16; ++rr) {
    int d = rr * 4 + tr;
    V8t[(size_t)(d0 + d) * SK_ + j0 + tc] = f2fp8(tile[tc][d] * sc);
  }
  // CS partial: thread (tr,tc) -> d = tc, j in [tr*16, tr*16+16)
  float s = 0.f;
  #pragma unroll
  for (int jj = 0; jj < 16; ++jj) {
    int j = tr * 16 + jj;
    s += tile[j][tc] * linv[j];
  }
  csred[tr][tc] = s;
  __syncthreads();
  if (tr == 0)
    cs_part[(size_t)blockIdx.x * DV_ + d0 + tc] =
        csred[0][tc] + csred[1][tc] + csred[2][tc] + csred[3][tc];
}

// CS[d] = sum of 64 partials. grid DV_/16, 2-D parallel reduce.
__global__ void cs_fin_kernel(const float* __restrict__ cs_part,
                              float* __restrict__ CS) {
  __shared__ float red[16][16];
  int d0 = blockIdx.x * 16;
  int t  = threadIdx.x;
  int dd = t & 15, pg = t >> 4;               // 16 partial-groups x 16 cols
  float s = 0.f;
  #pragma unroll
  for (int k = 0; k < 4; ++k)
    s += cs_part[(size_t)(pg * 4 + k) * DV_ + d0 + dd];
  red[pg][dd] = s;
  __syncthreads();
  if (pg == 0) {
    float tot = 0.f;
    #pragma unroll
    for (int k = 0; k < 16; ++k) tot += red[k][dd];
    CS[d0 + dd] = tot;
  }
}

// ============ fp8 MX GEMM: acc = A*B^T (A [M][K], B [N][K], K contig) ========
// MODE 0: store fp8(16*expm1(acc*scale))          (GEMM1: E-residual)
// MODE 1: store fp32 CS[col] + acc/65536          (GEMM2: output)
// LDS rows 128B = 8 x 16B slots, XOR-swizzled; gload_lds src pre-swizzled.
template <int FM, int FN, int MODE>
__global__ __launch_bounds__(256, 2)
void gemm8_kernel(const unsigned char* __restrict__ A,
                  const unsigned char* __restrict__ B,
                  void* __restrict__ Cout,
                  const float* __restrict__ CS,
                  int N, int K, float scale) {
  constexpr int BM = FM * 32;
  constexpr int BN = FN * 32;
  __shared__ __align__(16) unsigned char As[BM * 128];
  __shared__ __align__(16) unsigned char Bs[BN * 128];

  const int t    = threadIdx.x;
  const int lane = t & 63;
  const int wave = t >> 6;
  const int wr   = wave >> 1, wc = wave & 1;
  const int lr   = lane & 15;         // row(A frag) / col(B frag) / D col
  const int lk   = lane >> 4;         // k-block 0..3 (32 bytes each)

  const int m0 = blockIdx.y * BM;
  const int n0 = blockIdx.x * BN;

  f32x4 acc[FM][FN] = {};

  for (int k0 = 0; k0 < K; k0 += 128) {
    #pragma unroll
    for (int it = 0; it < FM; ++it) {
      int s = it * 256 + t;
      int row = s >> 3, p = s & 7;
      int k16 = p ^ (row & 7);
      gload_lds16(A + (size_t)(m0 + row) * K + k0 + k16 * 16, As + s * 16);
    }
    #pragma unroll
    for (int it = 0; it < FN; ++it) {
      int s = it * 256 + t;
      int row = s >> 3, p = s & 7;
      int k16 = p ^ (row & 7);
      gload_lds16(B + (size_t)(n0 + row) * K + k0 + k16 * 16, Bs + s * 16);
    }
    __syncthreads();

    i32x8 af[FM], bfr[FN];
    #pragma unroll
    for (int m = 0; m < FM; ++m) {
      int r = wr * (FM * 16) + m * 16 + lr;
      int s0 = (2 * lk) ^ (r & 7), s1 = (2 * lk + 1) ^ (r & 7);
      i32x4 lo = *reinterpret_cast<const i32x4*>(As + r * 128 + s0 * 16);
      i32x4 hi = *reinterpret_cast<const i32x4*>(As + r * 128 + s1 * 16);
      af[m][0] = lo[0]; af[m][1] = lo[1]; af[m][2] = lo[2]; af[m][3] = lo[3];
      af[m][4] = hi[0]; af[m][5] = hi[1]; af[m][6] = hi[2]; af[m][7] = hi[3];
    }
    #pragma unroll
    for (int n = 0; n < FN; ++n) {
      int r = wc * (FN * 16) + n * 16 + lr;
      int s0 = (2 * lk) ^ (r & 7), s1 = (2 * lk + 1) ^ (r & 7);
      i32x4 lo = *reinterpret_cast<const i32x4*>(Bs + r * 128 + s0 * 16);
      i32x4 hi = *reinterpret_cast<const i32x4*>(Bs + r * 128 + s1 * 16);
      bfr[n][0] = lo[0]; bfr[n][1] = lo[1]; bfr[n][2] = lo[2]; bfr[n][3] = lo[3];
      bfr[n][4] = hi[0]; bfr[n][5] = hi[1]; bfr[n][6] = hi[2]; bfr[n][7] = hi[3];
    }
    #pragma unroll
    for (int m = 0; m < FM; ++m)
      #pragma unroll
      for (int n = 0; n < FN; ++n)
        acc[m][n] = __builtin_amdgcn_mfma_scale_f32_16x16x128_f8f6f4(
            af[m], bfr[n], acc[m][n], 0, 0, 0, 127, 0, 127);
    __syncthreads();
  }

  const int orow0 = m0 + wr * (FM * 16) + lk * 4;
  const int ocol0 = n0 + wc * (FN * 16) + lr;
  if constexpr (MODE == 0) {
    unsigned char* E8 = (unsigned char*)Cout;
    #pragma unroll
    for (int m = 0; m < FM; ++m)
      #pragma unroll
      for (int n = 0; n < FN; ++n)
        #pragma unroll
        for (int r = 0; r < 4; ++r) {
          float s = acc[m][n][r] * scale;
          float e = s + 0.5f * s * s + (1.0f / 6.0f) * s * s * s;  // expm1
          E8[(size_t)(orow0 + m * 16 + r) * N + (ocol0 + n * 16)] =
              f2fp8(e * 16.0f);
        }
  } else {
    float* O = (float*)Cout;
    #pragma unroll
    for (int m = 0; m < FM; ++m)
      #pragma unroll
      for (int n = 0; n < FN; ++n) {
        float cs = CS[ocol0 + n * 16];
        #pragma unroll
        for (int r = 0; r < 4; ++r)
          O[(size_t)(orow0 + m * 16 + r) * N + (ocol0 + n * 16)] =
              cs + acc[m][n][r] * (1.0f / 65536.0f);
      }
  }
}

extern "C" void kernel_launch(void* const* d_in, const int* in_sizes, int n_in,
                              void* d_out, int out_size, void* d_ws,
                              size_t ws_size, hipStream_t stream) {
  const float* Q = (const float*)d_in[0];
  const float* K = (const float*)d_in[1];
  const float* V = (const float*)d_in[2];

  char* ws = (char*)d_ws;
  unsigned char* Q8    = (unsigned char*)(ws);                         // 4 MB
  unsigned char* K8    = (unsigned char*)(ws + ((size_t)4 << 20));     // 4 MB
  unsigned char* e8    = (unsigned char*)(ws + ((size_t)8 << 20));     // 16 MB
  unsigned char* V8t   = (unsigned char*)(ws + ((size_t)24 << 20));    // 4 MB
  float*         l     = (float*)(ws + ((size_t)28 << 20));            // 16 KB
  float*         CS    = (float*)(ws + ((size_t)28 << 20) + (16 << 10)); // 4 KB
  float*         part  = (float*)(ws + ((size_t)29 << 20));            // 1 MB
  float*         csp   = (float*)(ws + ((size_t)30 << 20));            // 256 KB

  conv8_kernel<<<SQ_ * D_ / 8 / 256, 256, 0, stream>>>(Q, (unsigned*)Q8,
                                                       SQ_ * D_ / 8);
  conv8_kernel<<<SK_ * D_ / 8 / 256, 256, 0, stream>>>(K, (unsigned*)K8,
                                                       SK_ * D_ / 8);

  // e8 = fp8(16*expm1(Q K^T / SK))
  gemm8_kernel<4, 4, 0><<<dim3(SK_ / 128, SQ_ / 128), 256, 0, stream>>>(
      Q8, K8, (void*)e8, nullptr, SK_, D_, 1.0f / (float)SK_);

  // l_j = 4096 + sum_i e8[i][j]/16  (64 partials, parallel fin)
  colsum8_part_kernel<<<dim3(SK_ / 1024, SQ_ / 64), 256, 0, stream>>>(e8, part);
  colsum8_fin_kernel<<<SK_ / 64, 256, 0, stream>>>(part, l);

  // V''t[d][j] = fp8(V[j][d]*4096/l[j]); CS partials [SK/64][DV]
  transv_cs_kernel<<<dim3(SK_ / 64, DV_ / 64), 256, 0, stream>>>(V, l, V8t, csp);
  cs_fin_kernel<<<DV_ / 16, 256, 0, stream>>>(csp, CS);

  // O[i][d] = CS[d] + (e8 @ V''t^T)/65536
  gemm8_kernel<2, 4, 1><<<dim3(DV_ / 128, SQ_ / 64), 256, 0, stream>>>(
      e8, V8t, d_out, CS, DV_, SK_, 1.0f);

  (void)in_sizes; (void)n_in; (void)out_size; (void)ws_size;
}

// Round 5
// 73.421 us; speedup vs baseline: 2.0649x; 1.2081x over previous
//
#include <hip/hip_runtime.h>
#include <hip/hip_bf16.h>
#include <stdint.h>

#define SQ_  4096
#define SK_  4096
#define D_   1024
#define DV_  1024

typedef __attribute__((ext_vector_type(4))) float  f32x4;
typedef __attribute__((ext_vector_type(4))) int    i32x4;
typedef __attribute__((ext_vector_type(8))) int    i32x8;

__device__ __forceinline__ unsigned char f2fp8(float v) {
  int d = __builtin_amdgcn_cvt_pk_fp8_f32(v, v, 0, false);
  return (unsigned char)(d & 0xff);
}

__device__ __forceinline__ void gload_lds16(const void* gp, void* lp) {
  auto g1 = reinterpret_cast<__attribute__((address_space(1))) uint32_t*>(
      reinterpret_cast<uintptr_t>(gp));
  auto l3 = reinterpret_cast<__attribute__((address_space(3))) uint32_t*>(
      reinterpret_cast<uintptr_t>(lp));
  __builtin_amdgcn_global_load_lds(g1, l3, 16, 0, 0);
}

// -------- fp32 -> fp8 e4m3 conversion, Q and K in one dispatch --------------
__global__ void conv8_dual_kernel(const float* __restrict__ Q,
                                  const float* __restrict__ Km,
                                  unsigned int* __restrict__ Q8,
                                  unsigned int* __restrict__ K8) {
  const int half = SQ_ * D_ / 8;
  int i = blockIdx.x * blockDim.x + threadIdx.x;
  const float* in = (i < half) ? Q : Km;
  unsigned int* out = (i < half) ? Q8 : K8;
  int ii = (i < half) ? i : i - half;
  const float4* p = reinterpret_cast<const float4*>(in) + (size_t)ii * 2;
  float4 v0 = p[0], v1 = p[1];
  int d0 = __builtin_amdgcn_cvt_pk_fp8_f32(v0.x, v0.y, 0, false);
  d0     = __builtin_amdgcn_cvt_pk_fp8_f32(v0.z, v0.w, d0, true);
  int d1 = __builtin_amdgcn_cvt_pk_fp8_f32(v1.x, v1.y, 0, false);
  d1     = __builtin_amdgcn_cvt_pk_fp8_f32(v1.z, v1.w, d1, true);
  uint2 o; o.x = (unsigned)d0; o.y = (unsigned)d1;
  reinterpret_cast<uint2*>(out)[ii] = o;
}

// l_j = 4096 + (sum of 32 row-block partials)/16.  grid SK_/64.
__global__ void colsum8_fin_kernel(const float* __restrict__ part,
                                   float* __restrict__ l) {
  __shared__ float red[4][64];
  int j0 = blockIdx.x * 64;
  int t  = threadIdx.x;
  int jj = t & 63, pg = t >> 6;               // 4 partial-groups x 64 cols
  float s = 0.f;
  #pragma unroll
  for (int k = 0; k < 8; ++k)
    s += part[(size_t)(pg * 8 + k) * SK_ + j0 + jj];
  red[pg][jj] = s;
  __syncthreads();
  if (pg == 0) {
    float tot = red[0][jj] + red[1][jj] + red[2][jj] + red[3][jj];
    l[j0 + jj] = 4096.0f + tot * (1.0f / 16.0f);
  }
}

// ------- V''t[d][j] = fp8(V[j][d]*4096/l[j])  +  CS partials ----------------
__global__ void transv_cs_kernel(const float* __restrict__ V,
                                 const float* __restrict__ l,
                                 unsigned char* __restrict__ V8t,
                                 float* __restrict__ cs_part) {
  __shared__ float tile[64][65];
  __shared__ float linv[64];
  __shared__ float csred[4][64];
  int j0 = blockIdx.x * 64;           // SK dim
  int d0 = blockIdx.y * 64;           // DV dim
  int t  = threadIdx.x;
  int tr = t >> 6;                    // 0..3
  int tc = t & 63;                    // 0..63
  if (t < 64) linv[t] = 1.0f / l[j0 + t];
  #pragma unroll
  for (int rr = 0; rr < 16; ++rr) {
    int j = rr * 4 + tr;
    tile[j][tc] = V[(size_t)(j0 + j) * DV_ + d0 + tc];
  }
  __syncthreads();
  float sc = 4096.0f * linv[tc];
  #pragma unroll
  for (int rr = 0; rr < 16; ++rr) {
    int d = rr * 4 + tr;
    V8t[(size_t)(d0 + d) * SK_ + j0 + tc] = f2fp8(tile[tc][d] * sc);
  }
  float s = 0.f;
  #pragma unroll
  for (int jj = 0; jj < 16; ++jj) {
    int j = tr * 16 + jj;
    s += tile[j][tc] * linv[j];
  }
  csred[tr][tc] = s;
  __syncthreads();
  if (tr == 0)
    cs_part[(size_t)blockIdx.x * DV_ + d0 + tc] =
        csred[0][tc] + csred[1][tc] + csred[2][tc] + csred[3][tc];
}

// CS[d] = sum of 64 partials. grid DV_/16.
__global__ void cs_fin_kernel(const float* __restrict__ cs_part,
                              float* __restrict__ CS) {
  __shared__ float red[16][16];
  int d0 = blockIdx.x * 16;
  int t  = threadIdx.x;
  int dd = t & 15, pg = t >> 4;
  float s = 0.f;
  #pragma unroll
  for (int k = 0; k < 4; ++k)
    s += cs_part[(size_t)(pg * 4 + k) * DV_ + d0 + dd];
  red[pg][dd] = s;
  __syncthreads();
  if (pg == 0) {
    float tot = 0.f;
    #pragma unroll
    for (int k = 0; k < 16; ++k) tot += red[k][dd];
    CS[d0 + dd] = tot;
  }
}

// ============ fp8 MX GEMM, 2-phase double-buffered (T3-minimum) ==============
// acc = A*B^T (A [M][K], B [N][K] bytes, K contig).
// MODE 0: store fp8(16*expm1(acc*scale)); fused column partials -> part[by][col]
// MODE 1: store fp32 CS[col] + acc/65536
// LDS rows 128B = 8 x 16B slots, XOR-swizzled; gload_lds src pre-swizzled.
template <int FM, int FN, int MODE>
__global__ __launch_bounds__(256, 2)
void gemm8_kernel(const unsigned char* __restrict__ A,
                  const unsigned char* __restrict__ B,
                  void* __restrict__ Cout,
                  const float* __restrict__ CS,
                  float* __restrict__ part,
                  int N, int K, float scale) {
  constexpr int BM = FM * 32;
  constexpr int BN = FN * 32;
  __shared__ __align__(16) unsigned char As[2][BM * 128];
  __shared__ __align__(16) unsigned char Bs[2][BN * 128];

  const int t    = threadIdx.x;
  const int lane = t & 63;
  const int wave = t >> 6;
  const int wr   = wave >> 1, wc = wave & 1;
  const int lr   = lane & 15;         // row(A frag) / col(B frag) / D col
  const int lk   = lane >> 4;         // k-block 0..3 (32 bytes each)

  const int m0 = blockIdx.y * BM;
  const int n0 = blockIdx.x * BN;

  f32x4 acc[FM][FN] = {};

  auto stage = [&](int buf, int k0) {
    #pragma unroll
    for (int it = 0; it < FM; ++it) {
      int s = it * 256 + t;
      int row = s >> 3, p = s & 7;
      int k16 = p ^ (row & 7);
      gload_lds16(A + (size_t)(m0 + row) * K + k0 + k16 * 16,
                  &As[buf][s * 16]);
    }
    #pragma unroll
    for (int it = 0; it < FN; ++it) {
      int s = it * 256 + t;
      int row = s >> 3, p = s & 7;
      int k16 = p ^ (row & 7);
      gload_lds16(B + (size_t)(n0 + row) * K + k0 + k16 * 16,
                  &Bs[buf][s * 16]);
    }
  };

  stage(0, 0);
  __syncthreads();                    // drains vmcnt(0): buf0 ready
  int cur = 0;
  for (int k0 = 0; k0 < K; k0 += 128) {
    if (k0 + 128 < K) stage(cur ^ 1, k0 + 128);   // prefetch overlaps MFMA

    i32x8 af[FM], bfr[FN];
    #pragma unroll
    for (int m = 0; m < FM; ++m) {
      int r = wr * (FM * 16) + m * 16 + lr;
      int s0 = (2 * lk) ^ (r & 7), s1 = (2 * lk + 1) ^ (r & 7);
      i32x4 lo = *reinterpret_cast<const i32x4*>(&As[cur][r * 128 + s0 * 16]);
      i32x4 hi = *reinterpret_cast<const i32x4*>(&As[cur][r * 128 + s1 * 16]);
      af[m][0] = lo[0]; af[m][1] = lo[1]; af[m][2] = lo[2]; af[m][3] = lo[3];
      af[m][4] = hi[0]; af[m][5] = hi[1]; af[m][6] = hi[2]; af[m][7] = hi[3];
    }
    #pragma unroll
    for (int n = 0; n < FN; ++n) {
      int r = wc * (FN * 16) + n * 16 + lr;
      int s0 = (2 * lk) ^ (r & 7), s1 = (2 * lk + 1) ^ (r & 7);
      i32x4 lo = *reinterpret_cast<const i32x4*>(&Bs[cur][r * 128 + s0 * 16]);
      i32x4 hi = *reinterpret_cast<const i32x4*>(&Bs[cur][r * 128 + s1 * 16]);
      bfr[n][0] = lo[0]; bfr[n][1] = lo[1]; bfr[n][2] = lo[2]; bfr[n][3] = lo[3];
      bfr[n][4] = hi[0]; bfr[n][5] = hi[1]; bfr[n][6] = hi[2]; bfr[n][7] = hi[3];
    }
    #pragma unroll
    for (int m = 0; m < FM; ++m)
      #pragma unroll
      for (int n = 0; n < FN; ++n)
        acc[m][n] = __builtin_amdgcn_mfma_scale_f32_16x16x128_f8f6f4(
            af[m], bfr[n], acc[m][n], 0, 0, 0, 127, 0, 127);

    __syncthreads();                  // one barrier/K-step: drains vm+lgkm
    cur ^= 1;
  }

  const int orow0 = m0 + wr * (FM * 16) + lk * 4;
  const int ocol0 = n0 + wc * (FN * 16) + lr;
  if constexpr (MODE == 0) {
    unsigned char* E8 = (unsigned char*)Cout;
    float csum[FN];
    #pragma unroll
    for (int n = 0; n < FN; ++n) csum[n] = 0.f;
    #pragma unroll
    for (int m = 0; m < FM; ++m)
      #pragma unroll
      for (int n = 0; n < FN; ++n)
        #pragma unroll
        for (int r = 0; r < 4; ++r) {
          float s = acc[m][n][r] * scale;
          float e16 = (s + 0.5f * s * s + (1.0f / 6.0f) * s * s * s) * 16.0f;
          csum[n] += e16;
          E8[(size_t)(orow0 + m * 16 + r) * N + (ocol0 + n * 16)] =
              f2fp8(e16);
        }
    // reduce over lk (lanes xor 16, 32) -> column partial for this wr-half
    #pragma unroll
    for (int n = 0; n < FN; ++n) {
      csum[n] += __shfl_xor(csum[n], 16, 64);
      csum[n] += __shfl_xor(csum[n], 32, 64);
    }
    float* scr = (float*)&As[0][0];   // 128 floats scratch (tile reads done)
    if (wr == 0 && lane < 16) {
      #pragma unroll
      for (int n = 0; n < FN; ++n)
        scr[wc * (FN * 16) + n * 16 + lane] = csum[n];
    }
    __syncthreads();
    if (wr == 1 && lane < 16) {
      #pragma unroll
      for (int n = 0; n < FN; ++n)
        part[(size_t)blockIdx.y * SK_ + n0 + wc * (FN * 16) + n * 16 + lane] =
            scr[wc * (FN * 16) + n * 16 + lane] + csum[n];
    }
  } else {
    float* O = (float*)Cout;
    #pragma unroll
    for (int m = 0; m < FM; ++m)
      #pragma unroll
      for (int n = 0; n < FN; ++n) {
        float cs = CS[ocol0 + n * 16];
        #pragma unroll
        for (int r = 0; r < 4; ++r)
          O[(size_t)(orow0 + m * 16 + r) * N + (ocol0 + n * 16)] =
              cs + acc[m][n][r] * (1.0f / 65536.0f);
      }
  }
}

extern "C" void kernel_launch(void* const* d_in, const int* in_sizes, int n_in,
                              void* d_out, int out_size, void* d_ws,
                              size_t ws_size, hipStream_t stream) {
  const float* Q = (const float*)d_in[0];
  const float* K = (const float*)d_in[1];
  const float* V = (const float*)d_in[2];

  char* ws = (char*)d_ws;
  unsigned char* Q8    = (unsigned char*)(ws);                         // 4 MB
  unsigned char* K8    = (unsigned char*)(ws + ((size_t)4 << 20));     // 4 MB
  unsigned char* e8    = (unsigned char*)(ws + ((size_t)8 << 20));     // 16 MB
  unsigned char* V8t   = (unsigned char*)(ws + ((size_t)24 << 20));    // 4 MB
  float*         l     = (float*)(ws + ((size_t)28 << 20));            // 16 KB
  float*         CS    = (float*)(ws + ((size_t)28 << 20) + (16 << 10)); // 4 KB
  float*         part  = (float*)(ws + ((size_t)29 << 20));            // 512 KB
  float*         csp   = (float*)(ws + ((size_t)30 << 20));            // 256 KB

  // Q and K -> fp8, one dispatch
  conv8_dual_kernel<<<(SQ_ + SK_) * D_ / 8 / 256, 256, 0, stream>>>(
      Q, K, (unsigned*)Q8, (unsigned*)K8);

  // e8 = fp8(16*expm1(Q K^T / SK)) + fused column partials part[32][SK]
  gemm8_kernel<4, 4, 0><<<dim3(SK_ / 128, SQ_ / 128), 256, 0, stream>>>(
      Q8, K8, (void*)e8, nullptr, part, SK_, D_, 1.0f / (float)SK_);

  // l_j = 4096 + sum partials/16
  colsum8_fin_kernel<<<SK_ / 64, 256, 0, stream>>>(part, l);

  // V''t[d][j] = fp8(V[j][d]*4096/l[j]); CS partials [SK/64][DV]
  transv_cs_kernel<<<dim3(SK_ / 64, DV_ / 64), 256, 0, stream>>>(V, l, V8t, csp);
  cs_fin_kernel<<<DV_ / 16, 256, 0, stream>>>(csp, CS);

  // O[i][d] = CS[d] + (e8 @ V''t^T)/65536
  gemm8_kernel<2, 4, 1><<<dim3(DV_ / 128, SQ_ / 64), 256, 0, stream>>>(
      e8, V8t, d_out, CS, nullptr, DV_, SK_, 1.0f);

  (void)in_sizes; (void)n_in; (void)out_size; (void)ws_size;
}

// Round 6
// 66.822 us; speedup vs baseline: 2.2688x; 1.0988x over previous
//
#include <hip/hip_runtime.h>
#include <hip/hip_bf16.h>
#include <stdint.h>

#define SQ_  4096
#define SK_  4096
#define D_   1024
#define DV_  1024

typedef __attribute__((ext_vector_type(4))) float  f32x4;
typedef __attribute__((ext_vector_type(4))) int    i32x4;
typedef __attribute__((ext_vector_type(8))) int    i32x8;

// fp4 e2m1 encode (RNE onto grid {0,.5,1,1.5,2,3,4,6}), returns 4-bit code.
__device__ __forceinline__ unsigned f2fp4(float x) {
  unsigned sgn = (__float_as_uint(x) >> 28) & 0x8u;
  float y = fabsf(x);
  unsigned c;
  if (y < 1.75f)      c = (unsigned)(int)rintf(y + y);  // codes 0..3 = 0,.5,1,1.5
  else if (y < 2.5f)  c = 4u;                           // 2
  else if (y < 3.5f)  c = 5u;                           // 3
  else if (y < 5.0f)  c = 6u;                           // 4
  else                c = 7u;                           // 6
  return sgn | c;
}

__device__ __forceinline__ void gload_lds16(const void* gp, void* lp) {
  auto g1 = reinterpret_cast<__attribute__((address_space(1))) uint32_t*>(
      reinterpret_cast<uintptr_t>(gp));
  auto l3 = reinterpret_cast<__attribute__((address_space(3))) uint32_t*>(
      reinterpret_cast<uintptr_t>(lp));
  __builtin_amdgcn_global_load_lds(g1, l3, 16, 0, 0);
}

// ---- fp32 -> fp4 (x2 scale), Q and K in one dispatch; 8 elems -> 1 uint ----
__global__ void conv4_dual_kernel(const float* __restrict__ Q,
                                  const float* __restrict__ Km,
                                  unsigned int* __restrict__ Q4,
                                  unsigned int* __restrict__ K4) {
  const int half = SQ_ * D_ / 8;
  int i = blockIdx.x * blockDim.x + threadIdx.x;
  const float* in = (i < half) ? Q : Km;
  unsigned int* out = (i < half) ? Q4 : K4;
  int ii = (i < half) ? i : i - half;
  const float4* p = reinterpret_cast<const float4*>(in) + (size_t)ii * 2;
  float4 v0 = p[0], v1 = p[1];
  unsigned w = 0;
  w |= f2fp4(2.0f * v0.x);
  w |= f2fp4(2.0f * v0.y) << 4;
  w |= f2fp4(2.0f * v0.z) << 8;
  w |= f2fp4(2.0f * v0.w) << 12;
  w |= f2fp4(2.0f * v1.x) << 16;
  w |= f2fp4(2.0f * v1.y) << 20;
  w |= f2fp4(2.0f * v1.z) << 24;
  w |= f2fp4(2.0f * v1.w) << 28;
  out[ii] = w;
}

// ---- transv: l-finalize + V4t[d][j] = fp4(V[j][d]*8192/l) + CS partials ----
__global__ void transv_cs_kernel(const float* __restrict__ V,
                                 const float* __restrict__ part,
                                 unsigned char* __restrict__ V4t,
                                 float* __restrict__ cs_part) {
  __shared__ float tile[64][65];
  __shared__ float linv[64];
  __shared__ float red[4][64];
  __shared__ float csred[4][64];
  int j0 = blockIdx.x * 64;           // SK dim
  int d0 = blockIdx.y * 64;           // DV dim
  int t  = threadIdx.x;
  int tr = t >> 6;                    // 0..3
  int tc = t & 63;                    // 0..63
  // l_j = 4096 + sum of 32 row-block partials (redundant per d-block, cheap)
  {
    float s = 0.f;
    #pragma unroll
    for (int k = 0; k < 8; ++k)
      s += part[(size_t)(tr * 8 + k) * SK_ + j0 + tc];
    red[tr][tc] = s;
  }
  #pragma unroll
  for (int rr = 0; rr < 16; ++rr) {
    int j = rr * 4 + tr;
    tile[j][tc] = V[(size_t)(j0 + j) * DV_ + d0 + tc];
  }
  __syncthreads();
  if (t < 64)
    linv[t] = 1.0f / (4096.0f + red[0][t] + red[1][t] + red[2][t] + red[3][t]);
  __syncthreads();
  float sc = 8192.0f * linv[tc];      // 2 * V * 4096 / l
  #pragma unroll
  for (int rr = 0; rr < 16; ++rr) {
    int d = rr * 4 + tr;
    unsigned c = f2fp4(tile[tc][d] * sc);
    unsigned pc = __shfl_xor(c, 1, 64);
    if ((tc & 1) == 0)
      V4t[(size_t)(d0 + d) * (SK_ / 2) + (j0 + tc) / 2] =
          (unsigned char)(c | (pc << 4));
  }
  float s = 0.f;
  #pragma unroll
  for (int jj = 0; jj < 16; ++jj) {
    int j = tr * 16 + jj;
    s += tile[j][tc] * linv[j];
  }
  csred[tr][tc] = s;
  __syncthreads();
  if (tr == 0)
    cs_part[(size_t)blockIdx.x * DV_ + d0 + tc] =
        csred[0][tc] + csred[1][tc] + csred[2][tc] + csred[3][tc];
}

// ============ fp4 MX GEMM, 2-phase double-buffered =========================
// acc = A*B^T; A [M][Kelem/2] bytes, B [N][Kelem/2] bytes (K contiguous).
// MODE 0 (GEMM1): store fp4(128*expm1(acc*scale)) nibbles + column partials
// MODE 1 (GEMM2): O = CS[col] + acc/1048576  (CS reduced in prologue)
// LDS rows 64B = 4 x 16B slots, slot-swizzle p ^ ((row>>1)&3) (2-way free);
// gload_lds source pre-swizzled (same involution).
template <int FM, int FN, int MODE>
__global__ __launch_bounds__(256, 2)
void gemm4_kernel(const unsigned char* __restrict__ A,
                  const unsigned char* __restrict__ B,
                  void* __restrict__ Cout,
                  const float* __restrict__ cs_part,
                  float* __restrict__ part,
                  int N, int Kelem, float scale) {
  constexpr int BM = FM * 32;
  constexpr int BN = FN * 32;
  __shared__ __align__(16) unsigned char As[2][BM * 64];
  __shared__ __align__(16) unsigned char Bs[2][BN * 64];
  __shared__ float csL[BN];

  const int t    = threadIdx.x;
  const int lane = t & 63;
  const int wave = t >> 6;
  const int wr   = wave >> 1, wc = wave & 1;
  const int lr   = lane & 15;         // row(A frag) / col(B frag) / D col
  const int lk   = lane >> 4;         // k-block 0..3 (16 bytes = 32 fp4 each)
  const int m0 = blockIdx.y * BM;
  const int n0 = blockIdx.x * BN;
  const int KB = Kelem / 2;           // row length in bytes

  if constexpr (MODE == 1) {
    if (t < BN) {
      float s = 0.f;
      #pragma unroll
      for (int p = 0; p < 64; ++p) s += cs_part[(size_t)p * DV_ + n0 + t];
      csL[t] = s;
    }
  }

  f32x4 acc[FM][FN] = {};

  auto stage = [&](int buf, int k0B) {
    #pragma unroll
    for (int it = 0; it < FM / 2; ++it) {
      int s = it * 256 + t;
      int row = s >> 2, p = s & 3;
      int pl = p ^ ((row >> 1) & 3);
      gload_lds16(A + (size_t)(m0 + row) * KB + k0B + pl * 16,
                  &As[buf][s * 16]);
    }
    #pragma unroll
    for (int it = 0; it < FN / 2; ++it) {
      int s = it * 256 + t;
      int row = s >> 2, p = s & 3;
      int pl = p ^ ((row >> 1) & 3);
      gload_lds16(B + (size_t)(n0 + row) * KB + k0B + pl * 16,
                  &Bs[buf][s * 16]);
    }
  };

  stage(0, 0);
  __syncthreads();
  int cur = 0;
  for (int k0B = 0; k0B < KB; k0B += 64) {
    if (k0B + 64 < KB) stage(cur ^ 1, k0B + 64);

    i32x8 af[FM], bfr[FN];
    #pragma unroll
    for (int m = 0; m < FM; ++m) {
      int r = wr * (FM * 16) + m * 16 + lr;
      int sl = lk ^ ((r >> 1) & 3);
      i32x4 lo = *reinterpret_cast<const i32x4*>(&As[cur][r * 64 + sl * 16]);
      af[m][0] = lo[0]; af[m][1] = lo[1]; af[m][2] = lo[2]; af[m][3] = lo[3];
      af[m][4] = 0; af[m][5] = 0; af[m][6] = 0; af[m][7] = 0;
    }
    #pragma unroll
    for (int n = 0; n < FN; ++n) {
      int r = wc * (FN * 16) + n * 16 + lr;
      int sl = lk ^ ((r >> 1) & 3);
      i32x4 lo = *reinterpret_cast<const i32x4*>(&Bs[cur][r * 64 + sl * 16]);
      bfr[n][0] = lo[0]; bfr[n][1] = lo[1]; bfr[n][2] = lo[2]; bfr[n][3] = lo[3];
      bfr[n][4] = 0; bfr[n][5] = 0; bfr[n][6] = 0; bfr[n][7] = 0;
    }
    #pragma unroll
    for (int m = 0; m < FM; ++m)
      #pragma unroll
      for (int n = 0; n < FN; ++n)
        acc[m][n] = __builtin_amdgcn_mfma_scale_f32_16x16x128_f8f6f4(
            af[m], bfr[n], acc[m][n], 4, 4, 0, 127, 0, 127);  // fmt 4 = fp4

    __syncthreads();
    cur ^= 1;
  }

  const int orow0 = m0 + wr * (FM * 16) + lk * 4;
  const int ocol0 = n0 + wc * (FN * 16) + lr;
  if constexpr (MODE == 0) {
    unsigned char* E4 = (unsigned char*)Cout;
    float csum[FN];
    #pragma unroll
    for (int n = 0; n < FN; ++n) csum[n] = 0.f;
    #pragma unroll
    for (int m = 0; m < FM; ++m)
      #pragma unroll
      for (int n = 0; n < FN; ++n)
        #pragma unroll
        for (int r = 0; r < 4; ++r) {
          float s = acc[m][n][r] * scale;
          float e = s + 0.5f * s * s + (1.0f / 6.0f) * s * s * s;  // expm1
          csum[n] += e;
          unsigned c = f2fp4(e * 128.0f);
          unsigned pc = __shfl_xor(c, 1, 64);
          if ((lr & 1) == 0)
            E4[(size_t)(orow0 + m * 16 + r) * (N / 2) +
               ((ocol0 + n * 16) >> 1)] = (unsigned char)(c | (pc << 4));
        }
    #pragma unroll
    for (int n = 0; n < FN; ++n) {
      csum[n] += __shfl_xor(csum[n], 16, 64);
      csum[n] += __shfl_xor(csum[n], 32, 64);
    }
    float* scr = (float*)&As[0][0];   // done with tiles; 128-float scratch
    if (wr == 0 && lane < 16) {
      #pragma unroll
      for (int n = 0; n < FN; ++n)
        scr[wc * (FN * 16) + n * 16 + lane] = csum[n];
    }
    __syncthreads();
    if (wr == 1 && lane < 16) {
      #pragma unroll
      for (int n = 0; n < FN; ++n)
        part[(size_t)blockIdx.y * SK_ + n0 + wc * (FN * 16) + n * 16 + lane] =
            scr[wc * (FN * 16) + n * 16 + lane] + csum[n];
    }
  } else {
    float* O = (float*)Cout;
    #pragma unroll
    for (int m = 0; m < FM; ++m)
      #pragma unroll
      for (int n = 0; n < FN; ++n) {
        float cs = csL[wc * (FN * 16) + n * 16 + lr];
        #pragma unroll
        for (int r = 0; r < 4; ++r)
          O[(size_t)(orow0 + m * 16 + r) * N + (ocol0 + n * 16)] =
              cs + acc[m][n][r] * (1.0f / 1048576.0f);
      }
  }
}

extern "C" void kernel_launch(void* const* d_in, const int* in_sizes, int n_in,
                              void* d_out, int out_size, void* d_ws,
                              size_t ws_size, hipStream_t stream) {
  const float* Q = (const float*)d_in[0];
  const float* K = (const float*)d_in[1];
  const float* V = (const float*)d_in[2];

  char* ws = (char*)d_ws;
  unsigned char* Q4   = (unsigned char*)(ws);                          // 2 MB
  unsigned char* K4   = (unsigned char*)(ws + ((size_t)2 << 20));      // 2 MB
  unsigned char* e4   = (unsigned char*)(ws + ((size_t)4 << 20));      // 8 MB
  unsigned char* V4t  = (unsigned char*)(ws + ((size_t)12 << 20));     // 2 MB
  float*         part = (float*)(ws + ((size_t)14 << 20));             // 512 KB
  float*         csp  = (float*)(ws + ((size_t)15 << 20));             // 256 KB

  // 1) Q,K -> fp4 (x2 scale)
  conv4_dual_kernel<<<(SQ_ + SK_) * D_ / 8 / 256, 256, 0, stream>>>(
      Q, K, (unsigned*)Q4, (unsigned*)K4);

  // 2) e4 = fp4(128*expm1(QK^T/4096)) + column partials part[32][SK]
  //    acc = 4*QK -> scale = 1/16384
  gemm4_kernel<4, 4, 0><<<dim3(SK_ / 128, SQ_ / 128), 256, 0, stream>>>(
      Q4, K4, (void*)e4, nullptr, part, SK_, D_, 1.0f / 16384.0f);

  // 3) l-finalize + V4t[d][j] = fp4(2*V[j][d]*4096/l) + CS partials [64][DV]
  transv_cs_kernel<<<dim3(SK_ / 64, DV_ / 64), 256, 0, stream>>>(
      V, part, V4t, csp);

  // 4) O[i][d] = CS[d] + acc/1048576  (CS reduced in-block from csp)
  gemm4_kernel<2, 4, 1><<<dim3(DV_ / 128, SQ_ / 64), 256, 0, stream>>>(
      e4, V4t, d_out, csp, nullptr, DV_, SK_, 1.0f);

  (void)in_sizes; (void)n_in; (void)out_size; (void)ws_size;
}